// Round 1
// baseline (417.929 us; speedup 1.0000x reference)
//
#include <hip/hip_runtime.h>
#include <math.h>

#define NB 10000      // nodes
#define BB 4          // batch
#define CC 128        // C = F_IN + UNITS
#define EE 160000     // edges
#define MM (NB * BB)  // 40000 GEMM rows
#define ROWC (BB * CC) // 512 floats per node row (N,B,C layout)

// ---------------- CSR build ----------------

__global__ void k_count(const int* __restrict__ dst, int* __restrict__ cnt) {
  int e = blockIdx.x * blockDim.x + threadIdx.x;
  if (e < EE) atomicAdd(&cnt[dst[e]], 1);
}

__global__ __launch_bounds__(1024) void k_scan(const int* __restrict__ cnt,
                                               int* __restrict__ off) {
  __shared__ int s_cnt[10240];
  __shared__ int s_sum[1024];
  int t = threadIdx.x;
  for (int i = t; i < 10240; i += 1024) s_cnt[i] = (i < NB) ? cnt[i] : 0;
  __syncthreads();
  int base = t * 10;
  int acc = 0;
  int loc[10];
#pragma unroll
  for (int i = 0; i < 10; ++i) { loc[i] = acc; acc += s_cnt[base + i]; }
  s_sum[t] = acc;
  __syncthreads();
  for (int d = 1; d < 1024; d <<= 1) {
    int v = (t >= d) ? s_sum[t - d] : 0;
    __syncthreads();
    s_sum[t] += v;
    __syncthreads();
  }
  int prev = (t == 0) ? 0 : s_sum[t - 1];
#pragma unroll
  for (int i = 0; i < 10; ++i) {
    int idx = base + i;
    if (idx <= NB) off[idx] = prev + loc[i];
  }
}

__global__ void k_fill(const int* __restrict__ src, const int* __restrict__ dst,
                       const float* __restrict__ ker, int* __restrict__ cur,
                       int* __restrict__ csrc, float* __restrict__ cker) {
  int e = blockIdx.x * blockDim.x + threadIdx.x;
  if (e < EE) {
    int p = atomicAdd(&cur[dst[e]], 1);
    csrc[p] = src[e];
    cker[p] = ker[e];
  }
}

// ---------------- concat builders (into (N,B,C) layout) ----------------

__global__ void k_build_xru(const float* __restrict__ in, const float* __restrict__ hx,
                            float* __restrict__ x) {
  int tid = blockIdx.x * blockDim.x + threadIdx.x;  // [0, MM*32)
  int m = tid >> 5;
  int c4 = (tid & 31) << 2;
  int n = m >> 2, b = m & 3;
  float4 v;
  if (c4 < 64) {
    v = *(const float4*)(in + ((size_t)(b * NB + n) * 64 + c4));
  } else {
    v = *(const float4*)(hx + ((size_t)(b * NB + n) * 64 + (c4 - 64)));
  }
  *(float4*)(x + (size_t)m * CC + c4) = v;
}

__global__ void k_build_xc(const float* __restrict__ in, const float* __restrict__ hx,
                           const float* __restrict__ ru, float* __restrict__ x) {
  int tid = blockIdx.x * blockDim.x + threadIdx.x;
  int m = tid >> 5;
  int c4 = (tid & 31) << 2;
  int n = m >> 2, b = m & 3;
  float4 v;
  if (c4 < 64) {
    v = *(const float4*)(in + ((size_t)(b * NB + n) * 64 + c4));
  } else {
    int c = c4 - 64;
    float4 h = *(const float4*)(hx + ((size_t)(b * NB + n) * 64 + c));
    float4 r = *(const float4*)(ru + ((size_t)m * CC + c));  // r = ru[:, :64]
    v.x = h.x * r.x; v.y = h.y * r.y; v.z = h.z * r.z; v.w = h.w * r.w;
  }
  *(float4*)(x + (size_t)m * CC + c4) = v;
}

// ---------------- sparse propagation hop (CSR gather, no atomics) ----------------

__global__ void k_prop(const float* __restrict__ x, float* __restrict__ y,
                       const int* __restrict__ roff, const int* __restrict__ csrc,
                       const float* __restrict__ cker) {
  int tid = blockIdx.x * blockDim.x + threadIdx.x;  // [0, NB*128)
  int n = tid >> 7;
  int q4 = (tid & 127) << 2;  // float offset in 512-float row
  int beg = roff[n], end = roff[n + 1];
  float4 acc = make_float4(0.f, 0.f, 0.f, 0.f);
  for (int i = beg; i < end; ++i) {
    int s = csrc[i];
    float kv = cker[i];
    float4 v = *(const float4*)(x + (size_t)s * ROWC + q4);
    acc.x += kv * v.x; acc.y += kv * v.y; acc.z += kv * v.z; acc.w += kv * v.w;
  }
  *(float4*)(y + (size_t)n * ROWC + q4) = acc;
}

// ---------------- fp32 tiled GEMM over 3 concatenated views ----------------
// h row m (contiguous per view): [v0[m,0:128] | v1[m,0:128] | v2[m,0:128]], K=384.
// BM=64, BK=32, BN=NC (128 or 64). 256 threads, 4 rows x (NC/16) cols each.

template <int NC, bool FINAL>
__global__ __launch_bounds__(256) void k_gemm(
    const float* __restrict__ v0, const float* __restrict__ v1,
    const float* __restrict__ v2, const float* __restrict__ W,
    const float* __restrict__ bias, float* __restrict__ ru,
    const float* __restrict__ hx, float* __restrict__ out) {
  __shared__ float As[32 * 64];
  __shared__ float Bs[32 * NC];
  const int tid = threadIdx.x;
  const int m0 = blockIdx.x * 64;
  const int rg = tid >> 4;  // 0..15 -> rows rg*4..+3
  const int cg = tid & 15;  // 0..15 -> cols cg*4..+3 (+64 block if NC=128)
  const int NCB = NC / 64;  // col blocks per thread

  float acc[4][NCB * 4];
#pragma unroll
  for (int i = 0; i < 4; ++i)
#pragma unroll
    for (int j = 0; j < NCB * 4; ++j) acc[i][j] = 0.f;

  for (int kt = 0; kt < 12; ++kt) {
    const int k0 = kt * 32;
    const float* hv = (k0 < 128) ? v0 : (k0 < 256) ? v1 : v2;
    const int kk0 = k0 & 127;
    // stage A tile (64 rows x 32 k) transposed -> As[k][m]
#pragma unroll
    for (int r = 0; r < 2; ++r) {
      int idx = tid + r * 256;          // [0,512)
      int ml = idx >> 3;                // row 0..63
      int k4 = (idx & 7) << 2;          // k offset 0..28
      float4 a = *(const float4*)(hv + (size_t)(m0 + ml) * CC + kk0 + k4);
      As[(k4 + 0) * 64 + ml] = a.x;
      As[(k4 + 1) * 64 + ml] = a.y;
      As[(k4 + 2) * 64 + ml] = a.z;
      As[(k4 + 3) * 64 + ml] = a.w;
    }
    // stage B tile (32 k x NC cols), row-major straight copy
#pragma unroll
    for (int r = 0; r < NC / 32; ++r) {
      int idx = tid + r * 256;          // [0, 8*NC)
      int k = idx / (NC / 4);
      int j4 = (idx % (NC / 4)) << 2;
      *(float4*)(Bs + k * NC + j4) = *(const float4*)(W + (size_t)(k0 + k) * NC + j4);
    }
    __syncthreads();
#pragma unroll
    for (int k = 0; k < 32; ++k) {
      float4 a = *(const float4*)(As + k * 64 + rg * 4);
#pragma unroll
      for (int cb = 0; cb < NCB; ++cb) {
        float4 b = *(const float4*)(Bs + k * NC + cb * 64 + cg * 4);
        acc[0][cb * 4 + 0] += a.x * b.x; acc[0][cb * 4 + 1] += a.x * b.y;
        acc[0][cb * 4 + 2] += a.x * b.z; acc[0][cb * 4 + 3] += a.x * b.w;
        acc[1][cb * 4 + 0] += a.y * b.x; acc[1][cb * 4 + 1] += a.y * b.y;
        acc[1][cb * 4 + 2] += a.y * b.z; acc[1][cb * 4 + 3] += a.y * b.w;
        acc[2][cb * 4 + 0] += a.z * b.x; acc[2][cb * 4 + 1] += a.z * b.y;
        acc[2][cb * 4 + 2] += a.z * b.z; acc[2][cb * 4 + 3] += a.z * b.w;
        acc[3][cb * 4 + 0] += a.w * b.x; acc[3][cb * 4 + 1] += a.w * b.y;
        acc[3][cb * 4 + 2] += a.w * b.z; acc[3][cb * 4 + 3] += a.w * b.w;
      }
    }
    __syncthreads();
  }

  if (!FINAL) {
    // ru = sigmoid(acc + bias), stored (N,B,128)
#pragma unroll
    for (int i = 0; i < 4; ++i) {
      int m = m0 + rg * 4 + i;
#pragma unroll
      for (int cb = 0; cb < NCB; ++cb) {
        int col0 = cb * 64 + cg * 4;
        float4 o;
        o.x = 1.f / (1.f + expf(-(acc[i][cb * 4 + 0] + bias[col0 + 0])));
        o.y = 1.f / (1.f + expf(-(acc[i][cb * 4 + 1] + bias[col0 + 1])));
        o.z = 1.f / (1.f + expf(-(acc[i][cb * 4 + 2] + bias[col0 + 2])));
        o.w = 1.f / (1.f + expf(-(acc[i][cb * 4 + 3] + bias[col0 + 3])));
        *(float4*)(ru + (size_t)m * 128 + col0) = o;
      }
    }
  } else {
    // out[b,n,:] = u*hx + (1-u)*tanh(acc + bias); u = ru[m, 64:128]
#pragma unroll
    for (int i = 0; i < 4; ++i) {
      int m = m0 + rg * 4 + i;
      int n = m >> 2, b = m & 3;
      int col0 = cg * 4;
      float4 u = *(const float4*)(ru + (size_t)m * 128 + 64 + col0);
      float4 h = *(const float4*)(hx + (size_t)(b * NB + n) * 64 + col0);
      float4 o;
      float c0 = tanhf(acc[i][0] + bias[col0 + 0]);
      float c1 = tanhf(acc[i][1] + bias[col0 + 1]);
      float c2 = tanhf(acc[i][2] + bias[col0 + 2]);
      float c3 = tanhf(acc[i][3] + bias[col0 + 3]);
      o.x = u.x * h.x + (1.f - u.x) * c0;
      o.y = u.y * h.y + (1.f - u.y) * c1;
      o.z = u.z * h.z + (1.f - u.z) * c2;
      o.w = u.w * h.w + (1.f - u.w) * c3;
      *(float4*)(out + (size_t)(b * NB + n) * 64 + col0) = o;
    }
  }
}

// ---------------- launch ----------------

extern "C" void kernel_launch(void* const* d_in, const int* in_sizes, int n_in,
                              void* d_out, int out_size, void* d_ws, size_t ws_size,
                              hipStream_t stream) {
  const float* d_inputs = (const float*)d_in[0];
  const float* d_hx     = (const float*)d_in[1];
  const int*   d_sidx   = (const int*)d_in[2];
  const float* d_ker    = (const float*)d_in[3];
  const float* d_Wru    = (const float*)d_in[4];
  const float* d_bru    = (const float*)d_in[5];
  const float* d_Wc     = (const float*)d_in[6];
  const float* d_bc     = (const float*)d_in[7];
  float* out = (float*)d_out;
  const int* src = d_sidx;
  const int* dst = d_sidx + EE;

  float* x    = (float*)d_ws;                 // (N,B,C) work tensor, 5.12M floats
  float* y1   = x + (size_t)MM * CC;
  float* y2   = y1 + (size_t)MM * CC;
  float* ru   = y2 + (size_t)MM * CC;         // (N,B,128) gates
  int*   cnt  = (int*)(ru + (size_t)MM * CC);
  int*   off  = cnt + NB;                     // NB+1
  int*   cur  = off + NB + 1;
  int*   csrc = cur + NB;                     // E
  float* cker = (float*)(csrc + EE);          // E

  // CSR build (per call: ws is poisoned before every launch)
  hipMemsetAsync(cnt, 0, NB * sizeof(int), stream);
  k_count<<<(EE + 255) / 256, 256, 0, stream>>>(dst, cnt);
  k_scan<<<1, 1024, 0, stream>>>(cnt, off);
  hipMemcpyAsync(cur, off, NB * sizeof(int), hipMemcpyDeviceToDevice, stream);
  k_fill<<<(EE + 255) / 256, 256, 0, stream>>>(src, dst, d_ker, cur, csrc, cker);

  // conv 1: x_ru -> y1 -> y2 -> ru gates
  k_build_xru<<<(MM * 32) / 256, 256, 0, stream>>>(d_inputs, d_hx, x);
  k_prop<<<(NB * 128) / 256, 256, 0, stream>>>(x, y1, off, csrc, cker);
  k_prop<<<(NB * 128) / 256, 256, 0, stream>>>(y1, y2, off, csrc, cker);
  k_gemm<128, false><<<MM / 64, 256, 0, stream>>>(x, y1, y2, d_Wru, d_bru, ru, nullptr, nullptr);

  // conv 2: x_c -> y1 -> y2 -> out
  k_build_xc<<<(MM * 32) / 256, 256, 0, stream>>>(d_inputs, d_hx, ru, x);
  k_prop<<<(NB * 128) / 256, 256, 0, stream>>>(x, y1, off, csrc, cker);
  k_prop<<<(NB * 128) / 256, 256, 0, stream>>>(y1, y2, off, csrc, cker);
  k_gemm<64, true><<<MM / 64, 256, 0, stream>>>(x, y1, y2, d_Wc, d_bc, ru, d_hx, out);
}

// Round 2
// 271.377 us; speedup vs baseline: 1.5400x; 1.5400x over previous
//
#include <hip/hip_runtime.h>
#include <hip/hip_bf16.h>
#include <math.h>

#define NB 10000      // nodes
#define BB 4          // batch
#define CC 128        // C = F_IN + UNITS
#define EE 160000     // edges
#define MM (NB * BB)  // 40000 GEMM rows

typedef __attribute__((ext_vector_type(8))) short short8;
typedef __attribute__((ext_vector_type(4))) float floatx4;

// ---------------- helpers ----------------

__device__ inline unsigned pk(float a, float b) {
  __hip_bfloat16 ha = __float2bfloat16(a), hb = __float2bfloat16(b);
  unsigned short ua = *(unsigned short*)&ha, ub = *(unsigned short*)&hb;
  return (unsigned)ua | ((unsigned)ub << 16);
}

__device__ inline void fma8(float* a, uint4 v, float k) {
  a[0] += k * __uint_as_float(v.x << 16);
  a[1] += k * __uint_as_float(v.x & 0xffff0000u);
  a[2] += k * __uint_as_float(v.y << 16);
  a[3] += k * __uint_as_float(v.y & 0xffff0000u);
  a[4] += k * __uint_as_float(v.z << 16);
  a[5] += k * __uint_as_float(v.z & 0xffff0000u);
  a[6] += k * __uint_as_float(v.w << 16);
  a[7] += k * __uint_as_float(v.w & 0xffff0000u);
}

// ---------------- CSR build ----------------

__global__ void k_count(const int* __restrict__ dst, int* __restrict__ cnt) {
  int e = blockIdx.x * blockDim.x + threadIdx.x;
  if (e < EE) atomicAdd(&cnt[dst[e]], 1);
}

__global__ __launch_bounds__(1024) void k_scan(const int* __restrict__ cnt,
                                               int* __restrict__ off) {
  __shared__ int s_cnt[10240];
  __shared__ int s_sum[1024];
  int t = threadIdx.x;
  for (int i = t; i < 10240; i += 1024) s_cnt[i] = (i < NB) ? cnt[i] : 0;
  __syncthreads();
  int base = t * 10;
  int acc = 0;
  int loc[10];
#pragma unroll
  for (int i = 0; i < 10; ++i) { loc[i] = acc; acc += s_cnt[base + i]; }
  s_sum[t] = acc;
  __syncthreads();
  for (int d = 1; d < 1024; d <<= 1) {
    int v = (t >= d) ? s_sum[t - d] : 0;
    __syncthreads();
    s_sum[t] += v;
    __syncthreads();
  }
  int prev = (t == 0) ? 0 : s_sum[t - 1];
#pragma unroll
  for (int i = 0; i < 10; ++i) {
    int idx = base + i;
    if (idx <= NB) off[idx] = prev + loc[i];
  }
}

__global__ void k_fill(const int* __restrict__ src, const int* __restrict__ dst,
                       const float* __restrict__ ker, int* __restrict__ cur,
                       uint2* __restrict__ edges) {
  int e = blockIdx.x * blockDim.x + threadIdx.x;
  if (e < EE) {
    int p = atomicAdd(&cur[dst[e]], 1);
    edges[p] = make_uint2((unsigned)src[e], __float_as_uint(ker[e]));
  }
}

// ---------------- W transpose + bf16 convert (Wt[n][k] = W[k][n]) ----------------

__global__ void k_convW(const float* __restrict__ Wru, const float* __restrict__ Wc,
                        ushort* __restrict__ Wtru, ushort* __restrict__ Wtc) {
  int t = blockIdx.x * blockDim.x + threadIdx.x;  // [0, 128*384)
  if (t < 128 * 384) {
    int nn = t / 384, kk = t % 384;
    __hip_bfloat16 h = __float2bfloat16(Wru[(size_t)kk * 128 + nn]);
    Wtru[t] = *(unsigned short*)&h;
  }
  if (t < 64 * 384) {
    int nn = t / 384, kk = t % 384;
    __hip_bfloat16 h = __float2bfloat16(Wc[(size_t)kk * 64 + nn]);
    Wtc[t] = *(unsigned short*)&h;
  }
}

// ---------------- concat builders into bf16 (N,B,C) rows ----------------

__global__ void k_build_xru(const float* __restrict__ in, const float* __restrict__ hx,
                            ushort* __restrict__ x) {
  int tid = blockIdx.x * blockDim.x + threadIdx.x;  // [0, MM*16)
  int m = tid >> 4;
  int c8 = (tid & 15) << 3;
  int n = m >> 2, b = m & 3;
  const float* sp = (c8 < 64) ? (in + (size_t)(b * NB + n) * 64 + c8)
                              : (hx + (size_t)(b * NB + n) * 64 + (c8 - 64));
  float4 f0 = *(const float4*)(sp);
  float4 f1 = *(const float4*)(sp + 4);
  uint4 o;
  o.x = pk(f0.x, f0.y); o.y = pk(f0.z, f0.w);
  o.z = pk(f1.x, f1.y); o.w = pk(f1.z, f1.w);
  *(uint4*)(x + (size_t)m * 128 + c8) = o;
}

__global__ void k_build_xc(const float* __restrict__ in, const float* __restrict__ hx,
                           const float* __restrict__ ru, ushort* __restrict__ x) {
  int tid = blockIdx.x * blockDim.x + threadIdx.x;
  int m = tid >> 4;
  int c8 = (tid & 15) << 3;
  int n = m >> 2, b = m & 3;
  float4 f0, f1;
  if (c8 < 64) {
    const float* sp = in + (size_t)(b * NB + n) * 64 + c8;
    f0 = *(const float4*)(sp);
    f1 = *(const float4*)(sp + 4);
  } else {
    const float* hp = hx + (size_t)(b * NB + n) * 64 + (c8 - 64);
    const float* rp = ru + (size_t)m * 128 + (c8 - 64);  // r = ru[:, :64]
    float4 h0 = *(const float4*)(hp), h1 = *(const float4*)(hp + 4);
    float4 r0 = *(const float4*)(rp), r1 = *(const float4*)(rp + 4);
    f0.x = h0.x * r0.x; f0.y = h0.y * r0.y; f0.z = h0.z * r0.z; f0.w = h0.w * r0.w;
    f1.x = h1.x * r1.x; f1.y = h1.y * r1.y; f1.z = h1.z * r1.z; f1.w = h1.w * r1.w;
  }
  uint4 o;
  o.x = pk(f0.x, f0.y); o.y = pk(f0.z, f0.w);
  o.z = pk(f1.x, f1.y); o.w = pk(f1.z, f1.w);
  *(uint4*)(x + (size_t)m * 128 + c8) = o;
}

// ---------------- sparse hop: one wave per node row (512 bf16 = 1KB) ----------------

__global__ __launch_bounds__(256) void k_prop(const ushort* __restrict__ x,
                                              ushort* __restrict__ y,
                                              const int* __restrict__ roff,
                                              const uint2* __restrict__ edges) {
  int tid = blockIdx.x * blockDim.x + threadIdx.x;  // [0, NB*64)
  int n = tid >> 6;
  int o8 = (tid & 63) << 3;  // 8 bf16 (16B) per lane
  int beg = roff[n], end = roff[n + 1];
  float acc[8];
#pragma unroll
  for (int j = 0; j < 8; ++j) acc[j] = 0.f;
  int i = beg;
  for (; i + 2 <= end; i += 2) {
    uint2 e0 = edges[i], e1 = edges[i + 1];
    uint4 v0 = *(const uint4*)(x + (size_t)e0.x * 512 + o8);
    uint4 v1 = *(const uint4*)(x + (size_t)e1.x * 512 + o8);
    fma8(acc, v0, __uint_as_float(e0.y));
    fma8(acc, v1, __uint_as_float(e1.y));
  }
  if (i < end) {
    uint2 e0 = edges[i];
    uint4 v0 = *(const uint4*)(x + (size_t)e0.x * 512 + o8);
    fma8(acc, v0, __uint_as_float(e0.y));
  }
  uint4 o;
  o.x = pk(acc[0], acc[1]); o.y = pk(acc[2], acc[3]);
  o.z = pk(acc[4], acc[5]); o.w = pk(acc[6], acc[7]);
  *(uint4*)(y + (size_t)n * 512 + o8) = o;
}

// ---------------- MFMA GEMM over 3 concatenated bf16 views, K=384 ----------------
// Block: 64 rows, 256 thr = 4 waves in 2x2. Wave: 32 rows x NT*16 cols.
// A frag: lane holds A[m=lane&15][k=quad*8+j] -> contiguous 16B in view row.
// B frag: lane holds B[k=quad*8+j][n=lane&15] -> contiguous 16B in Wt[n][k].
// D frag: col=lane&15, row=quad*4+reg.

template <int NT, bool FINAL>
__global__ __launch_bounds__(256) void k_gemm_mfma(
    const ushort* __restrict__ v0, const ushort* __restrict__ v1,
    const ushort* __restrict__ v2, const ushort* __restrict__ Wt,
    const float* __restrict__ bias, float* __restrict__ ru,
    const float* __restrict__ hx, float* __restrict__ out) {
  const int tid = threadIdx.x;
  const int lane = tid & 63;
  const int w = tid >> 6;
  const int wm = w >> 1, wn = w & 1;
  const int m0 = blockIdx.x * 64 + wm * 32;
  const int col0 = wn * (NT * 16);
  const int lr = lane & 15;
  const int quad = lane >> 4;
  const int koff = quad * 8;

  floatx4 acc[2][NT];
#pragma unroll
  for (int a = 0; a < 2; ++a)
#pragma unroll
    for (int b = 0; b < NT; ++b) acc[a][b] = {0.f, 0.f, 0.f, 0.f};

  const ushort* views[3] = {v0, v1, v2};
  for (int kt = 0; kt < 12; ++kt) {
    const ushort* hv = views[kt >> 2];
    const int kk = ((kt & 3) << 5) + koff;   // k offset within view
    const int kg = (kt << 5) + koff;         // global k offset for Wt
    short8 a0 = *(const short8*)(hv + (size_t)(m0 + lr) * 128 + kk);
    short8 a1 = *(const short8*)(hv + (size_t)(m0 + 16 + lr) * 128 + kk);
#pragma unroll
    for (int nt = 0; nt < NT; ++nt) {
      short8 b = *(const short8*)(Wt + (size_t)(col0 + nt * 16 + lr) * 384 + kg);
      acc[0][nt] = __builtin_amdgcn_mfma_f32_16x16x32_bf16(a0, b, acc[0][nt], 0, 0, 0);
      acc[1][nt] = __builtin_amdgcn_mfma_f32_16x16x32_bf16(a1, b, acc[1][nt], 0, 0, 0);
    }
  }

#pragma unroll
  for (int mt = 0; mt < 2; ++mt) {
#pragma unroll
    for (int nt = 0; nt < NT; ++nt) {
      int col = col0 + nt * 16 + lr;
      float bv = bias[col];
#pragma unroll
      for (int i = 0; i < 4; ++i) {
        int m = m0 + mt * 16 + quad * 4 + i;
        float val = acc[mt][nt][i] + bv;
        if (!FINAL) {
          ru[(size_t)m * 128 + col] = 1.f / (1.f + expf(-val));
        } else {
          int n = m >> 2, b2 = m & 3;
          float u = ru[(size_t)m * 128 + 64 + col];
          float h = hx[(size_t)(b2 * NB + n) * 64 + col];
          float c = tanhf(val);
          out[(size_t)(b2 * NB + n) * 64 + col] = u * h + (1.f - u) * c;
        }
      }
    }
  }
}

// ---------------- launch ----------------

extern "C" void kernel_launch(void* const* d_in, const int* in_sizes, int n_in,
                              void* d_out, int out_size, void* d_ws, size_t ws_size,
                              hipStream_t stream) {
  const float* d_inputs = (const float*)d_in[0];
  const float* d_hx     = (const float*)d_in[1];
  const int*   d_sidx   = (const int*)d_in[2];
  const float* d_ker    = (const float*)d_in[3];
  const float* d_Wru    = (const float*)d_in[4];
  const float* d_bru    = (const float*)d_in[5];
  const float* d_Wc     = (const float*)d_in[6];
  const float* d_bc     = (const float*)d_in[7];
  float* out = (float*)d_out;
  const int* src = d_sidx;
  const int* dst = d_sidx + EE;

  // workspace layout (16B-aligned chunks)
  ushort* x    = (ushort*)d_ws;                    // MM*128 bf16
  ushort* y1   = x + (size_t)MM * 128;
  ushort* y2   = y1 + (size_t)MM * 128;
  float*  ru   = (float*)(y2 + (size_t)MM * 128);  // MM*128 fp32 gates
  ushort* Wtru = (ushort*)(ru + (size_t)MM * 128); // 128*384
  ushort* Wtc  = Wtru + 128 * 384;                 // 64*384
  uint2*  edges = (uint2*)(Wtc + 64 * 384);        // EE
  int*    cnt  = (int*)(edges + EE);
  int*    off  = cnt + NB;                         // NB+1
  int*    cur  = off + NB + 1;

  // CSR build (ws is re-poisoned before every launch; rebuild each call)
  hipMemsetAsync(cnt, 0, NB * sizeof(int), stream);
  k_count<<<(EE + 255) / 256, 256, 0, stream>>>(dst, cnt);
  k_scan<<<1, 1024, 0, stream>>>(cnt, off);
  hipMemcpyAsync(cur, off, NB * sizeof(int), hipMemcpyDeviceToDevice, stream);
  k_fill<<<(EE + 255) / 256, 256, 0, stream>>>(src, dst, d_ker, cur, edges);
  k_convW<<<(128 * 384 + 255) / 256, 256, 0, stream>>>(d_Wru, d_Wc, Wtru, Wtc);

  // conv 1: x_ru -> y1 -> y2 -> ru gates (sigmoid)
  k_build_xru<<<(MM * 16) / 256, 256, 0, stream>>>(d_inputs, d_hx, x);
  k_prop<<<(NB * 64) / 256, 256, 0, stream>>>(x, y1, off, edges);
  k_prop<<<(NB * 64) / 256, 256, 0, stream>>>(y1, y2, off, edges);
  k_gemm_mfma<4, false><<<MM / 64, 256, 0, stream>>>(x, y1, y2, Wtru, d_bru, ru, nullptr, nullptr);

  // conv 2: x_c -> y1 -> y2 -> out (tanh + GRU gate)
  k_build_xc<<<(MM * 16) / 256, 256, 0, stream>>>(d_inputs, d_hx, ru, x);
  k_prop<<<(NB * 64) / 256, 256, 0, stream>>>(x, y1, off, edges);
  k_prop<<<(NB * 64) / 256, 256, 0, stream>>>(y1, y2, off, edges);
  k_gemm_mfma<2, true><<<MM / 64, 256, 0, stream>>>(x, y1, y2, Wtc, d_bc, ru, d_hx, out);
}

// Round 3
// 247.399 us; speedup vs baseline: 1.6893x; 1.0969x over previous
//
#include <hip/hip_runtime.h>
#include <hip/hip_bf16.h>
#include <math.h>

#define NB 10000      // nodes
#define BB 4          // batch
#define CC 128        // C = F_IN + UNITS
#define EE 160000     // edges
#define MM (NB * BB)  // 40000 GEMM rows

typedef __attribute__((ext_vector_type(8))) short short8;
typedef __attribute__((ext_vector_type(4))) float floatx4;

struct ViewTab {
  const ushort* base[12];
  int stride[12];
};

// ---------------- helpers ----------------

__device__ inline unsigned pk(float a, float b) {
  __hip_bfloat16 ha = __float2bfloat16(a), hb = __float2bfloat16(b);
  unsigned short ua = *(unsigned short*)&ha, ub = *(unsigned short*)&hb;
  return (unsigned)ua | ((unsigned)ub << 16);
}

__device__ inline void fma8(float* a, uint4 v, float k) {
  a[0] += k * __uint_as_float(v.x << 16);
  a[1] += k * __uint_as_float(v.x & 0xffff0000u);
  a[2] += k * __uint_as_float(v.y << 16);
  a[3] += k * __uint_as_float(v.y & 0xffff0000u);
  a[4] += k * __uint_as_float(v.z << 16);
  a[5] += k * __uint_as_float(v.z & 0xffff0000u);
  a[6] += k * __uint_as_float(v.w << 16);
  a[7] += k * __uint_as_float(v.w & 0xffff0000u);
}

// ---------------- CSR build ----------------

__global__ void k_count(const int* __restrict__ dst, int* __restrict__ cnt) {
  int e = blockIdx.x * blockDim.x + threadIdx.x;
  if (e < EE) atomicAdd(&cnt[dst[e]], 1);
}

__global__ __launch_bounds__(1024) void k_scan(const int* __restrict__ cnt,
                                               int* __restrict__ off,
                                               int* __restrict__ cur) {
  __shared__ int s_cnt[10240];
  __shared__ int s_sum[1024];
  int t = threadIdx.x;
  for (int i = t; i < 10240; i += 1024) s_cnt[i] = (i < NB) ? cnt[i] : 0;
  __syncthreads();
  int base = t * 10;
  int acc = 0;
  int loc[10];
#pragma unroll
  for (int i = 0; i < 10; ++i) { loc[i] = acc; acc += s_cnt[base + i]; }
  s_sum[t] = acc;
  __syncthreads();
  for (int d = 1; d < 1024; d <<= 1) {
    int v = (t >= d) ? s_sum[t - d] : 0;
    __syncthreads();
    s_sum[t] += v;
    __syncthreads();
  }
  int prev = (t == 0) ? 0 : s_sum[t - 1];
#pragma unroll
  for (int i = 0; i < 10; ++i) {
    int idx = base + i;
    int val = prev + loc[i];
    if (idx <= NB) off[idx] = val;
    if (idx < NB) cur[idx] = val;
  }
}

__global__ void k_fill(const int* __restrict__ src, const int* __restrict__ dst,
                       const float* __restrict__ ker, int* __restrict__ cur,
                       uint2* __restrict__ edges) {
  int e = blockIdx.x * blockDim.x + threadIdx.x;
  if (e < EE) {
    int p = atomicAdd(&cur[dst[e]], 1);
    edges[p] = make_uint2((unsigned)src[e], __float_as_uint(ker[e]));
  }
}

// ---------------- W transpose + bf16 convert (Wt[n][k] = W[k][n]) ----------------

__global__ void k_convW(const float* __restrict__ Wru, const float* __restrict__ Wc,
                        ushort* __restrict__ Wtru, ushort* __restrict__ Wtc) {
  int t = blockIdx.x * blockDim.x + threadIdx.x;  // [0, 128*384)
  if (t < 128 * 384) {
    int nn = t / 384, kk = t % 384;
    __hip_bfloat16 h = __float2bfloat16(Wru[(size_t)kk * 128 + nn]);
    Wtru[t] = *(unsigned short*)&h;
  }
  if (t < 64 * 384) {
    int nn = t / 384, kk = t % 384;
    __hip_bfloat16 h = __float2bfloat16(Wc[(size_t)kk * 64 + nn]);
    Wtc[t] = *(unsigned short*)&h;
  }
}

// ---------------- concat builder into bf16 (N,B,C) rows ----------------

__global__ void k_build_xru(const float* __restrict__ in, const float* __restrict__ hx,
                            ushort* __restrict__ x) {
  int tid = blockIdx.x * blockDim.x + threadIdx.x;  // [0, MM*16)
  int m = tid >> 4;
  int c8 = (tid & 15) << 3;
  int n = m >> 2, b = m & 3;
  const float* sp = (c8 < 64) ? (in + (size_t)(b * NB + n) * 64 + c8)
                              : (hx + (size_t)(b * NB + n) * 64 + (c8 - 64));
  float4 f0 = *(const float4*)(sp);
  float4 f1 = *(const float4*)(sp + 4);
  uint4 o;
  o.x = pk(f0.x, f0.y); o.y = pk(f0.z, f0.w);
  o.z = pk(f1.x, f1.y); o.w = pk(f1.z, f1.w);
  *(uint4*)(x + (size_t)m * 128 + c8) = o;
}

// rh = bf16(r * hx), (N,B,64); r = ru[:, :64]
__global__ void k_build_rh(const float* __restrict__ ru, const float* __restrict__ hx,
                           ushort* __restrict__ rh) {
  int tid = blockIdx.x * blockDim.x + threadIdx.x;  // [0, MM*8)
  int m = tid >> 3;
  int c8 = (tid & 7) << 3;
  int n = m >> 2, b = m & 3;
  const float* rp = ru + (size_t)m * 128 + c8;
  const float* hp = hx + (size_t)(b * NB + n) * 64 + c8;
  float4 r0 = *(const float4*)rp, r1 = *(const float4*)(rp + 4);
  float4 h0 = *(const float4*)hp, h1 = *(const float4*)(hp + 4);
  uint4 o;
  o.x = pk(r0.x * h0.x, r0.y * h0.y);
  o.y = pk(r0.z * h0.z, r0.w * h0.w);
  o.z = pk(r1.x * h1.x, r1.y * h1.y);
  o.w = pk(r1.z * h1.z, r1.w * h1.w);
  *(uint4*)(rh + (size_t)m * 64 + c8) = o;
}

// ---------------- sparse hops (CSR gather, fp32 accum, bf16 in/out) ----------------

// 128-ch rows (512 bf16 = 1KB per node): one wave per node, 16B/lane.
__global__ __launch_bounds__(256) void k_prop(const ushort* __restrict__ x,
                                              ushort* __restrict__ y,
                                              const int* __restrict__ roff,
                                              const uint2* __restrict__ edges) {
  int tid = blockIdx.x * blockDim.x + threadIdx.x;  // [0, NB*64)
  int n = tid >> 6;
  int o8 = (tid & 63) << 3;
  int beg = roff[n], end = roff[n + 1];
  float acc[8];
#pragma unroll
  for (int j = 0; j < 8; ++j) acc[j] = 0.f;
  int i = beg;
  for (; i + 2 <= end; i += 2) {
    uint2 e0 = edges[i], e1 = edges[i + 1];
    uint4 v0 = *(const uint4*)(x + (size_t)e0.x * 512 + o8);
    uint4 v1 = *(const uint4*)(x + (size_t)e1.x * 512 + o8);
    fma8(acc, v0, __uint_as_float(e0.y));
    fma8(acc, v1, __uint_as_float(e1.y));
  }
  if (i < end) {
    uint2 e0 = edges[i];
    uint4 v0 = *(const uint4*)(x + (size_t)e0.x * 512 + o8);
    fma8(acc, v0, __uint_as_float(e0.y));
  }
  uint4 o;
  o.x = pk(acc[0], acc[1]); o.y = pk(acc[2], acc[3]);
  o.z = pk(acc[4], acc[5]); o.w = pk(acc[6], acc[7]);
  *(uint4*)(y + (size_t)n * 512 + o8) = o;
}

// 64-ch rows (256 bf16 = 512B per node): half-wave per node, 16B/lane.
__global__ __launch_bounds__(256) void k_prop64(const ushort* __restrict__ x,
                                                ushort* __restrict__ y,
                                                const int* __restrict__ roff,
                                                const uint2* __restrict__ edges) {
  int tid = blockIdx.x * blockDim.x + threadIdx.x;  // [0, NB*32)
  int n = tid >> 5;
  int o8 = (tid & 31) << 3;
  int beg = roff[n], end = roff[n + 1];
  float acc[8];
#pragma unroll
  for (int j = 0; j < 8; ++j) acc[j] = 0.f;
  int i = beg;
  for (; i + 2 <= end; i += 2) {
    uint2 e0 = edges[i], e1 = edges[i + 1];
    uint4 v0 = *(const uint4*)(x + (size_t)e0.x * 256 + o8);
    uint4 v1 = *(const uint4*)(x + (size_t)e1.x * 256 + o8);
    fma8(acc, v0, __uint_as_float(e0.y));
    fma8(acc, v1, __uint_as_float(e1.y));
  }
  if (i < end) {
    uint2 e0 = edges[i];
    uint4 v0 = *(const uint4*)(x + (size_t)e0.x * 256 + o8);
    fma8(acc, v0, __uint_as_float(e0.y));
  }
  uint4 o;
  o.x = pk(acc[0], acc[1]); o.y = pk(acc[2], acc[3]);
  o.z = pk(acc[4], acc[5]); o.w = pk(acc[6], acc[7]);
  *(uint4*)(y + (size_t)n * 256 + o8) = o;
}

// ---------------- MFMA GEMM, K=384 stitched from a per-32k-tile view table ----------
// Block: 64 rows, 4 waves in 2x2. Wave: 32 rows x NT*16 cols.
// A frag: lane holds A[m=lane&15][k=quad*8+j] -> contiguous 16B per view row.
// B frag: lane holds B[k=quad*8+j][n=lane&15] -> contiguous 16B in Wt[n][k].
// D frag: col=lane&15, row=quad*4+reg.

template <int NT, bool FINAL>
__global__ __launch_bounds__(256) void k_gemm_mfma(
    ViewTab V, const ushort* __restrict__ Wt,
    const float* __restrict__ bias, float* __restrict__ ru,
    const float* __restrict__ hx, float* __restrict__ out) {
  const int tid = threadIdx.x;
  const int lane = tid & 63;
  const int w = tid >> 6;
  const int wm = w >> 1, wn = w & 1;
  const int m0 = blockIdx.x * 64 + wm * 32;
  const int col0 = wn * (NT * 16);
  const int lr = lane & 15;
  const int quad = lane >> 4;
  const int koff = quad * 8;

  floatx4 acc[2][NT];
#pragma unroll
  for (int a = 0; a < 2; ++a)
#pragma unroll
    for (int b = 0; b < NT; ++b) acc[a][b] = {0.f, 0.f, 0.f, 0.f};

#pragma unroll
  for (int kt = 0; kt < 12; ++kt) {
    const ushort* bp = V.base[kt];
    const int st = V.stride[kt];
    const int kg = (kt << 5) + koff;  // global k for Wt
    short8 a0 = *(const short8*)(bp + (size_t)(m0 + lr) * st + koff);
    short8 a1 = *(const short8*)(bp + (size_t)(m0 + 16 + lr) * st + koff);
#pragma unroll
    for (int nt = 0; nt < NT; ++nt) {
      short8 b = *(const short8*)(Wt + (size_t)(col0 + nt * 16 + lr) * 384 + kg);
      acc[0][nt] = __builtin_amdgcn_mfma_f32_16x16x32_bf16(a0, b, acc[0][nt], 0, 0, 0);
      acc[1][nt] = __builtin_amdgcn_mfma_f32_16x16x32_bf16(a1, b, acc[1][nt], 0, 0, 0);
    }
  }

#pragma unroll
  for (int mt = 0; mt < 2; ++mt) {
#pragma unroll
    for (int nt = 0; nt < NT; ++nt) {
      int col = col0 + nt * 16 + lr;
      float bv = bias[col];
#pragma unroll
      for (int i = 0; i < 4; ++i) {
        int m = m0 + mt * 16 + quad * 4 + i;
        float val = acc[mt][nt][i] + bv;
        if (!FINAL) {
          ru[(size_t)m * 128 + col] = 1.f / (1.f + expf(-val));
        } else {
          int n = m >> 2, b2 = m & 3;
          float u = ru[(size_t)m * 128 + 64 + col];
          float h = hx[(size_t)(b2 * NB + n) * 64 + col];
          float c = tanhf(val);
          out[(size_t)(b2 * NB + n) * 64 + col] = u * h + (1.f - u) * c;
        }
      }
    }
  }
}

// ---------------- launch ----------------

extern "C" void kernel_launch(void* const* d_in, const int* in_sizes, int n_in,
                              void* d_out, int out_size, void* d_ws, size_t ws_size,
                              hipStream_t stream) {
  const float* d_inputs = (const float*)d_in[0];
  const float* d_hx     = (const float*)d_in[1];
  const int*   d_sidx   = (const int*)d_in[2];
  const float* d_ker    = (const float*)d_in[3];
  const float* d_Wru    = (const float*)d_in[4];
  const float* d_bru    = (const float*)d_in[5];
  const float* d_Wc     = (const float*)d_in[6];
  const float* d_bc     = (const float*)d_in[7];
  float* out = (float*)d_out;
  const int* src = d_sidx;
  const int* dst = d_sidx + EE;

  // workspace layout (16B-aligned chunks)
  ushort* x    = (ushort*)d_ws;                    // MM*128 bf16 [in|hx]
  ushort* y1   = x + (size_t)MM * 128;             // A [in|hx]
  ushort* y2   = y1 + (size_t)MM * 128;            // A^2 [in|hx]
  ushort* rh0  = y2 + (size_t)MM * 128;            // MM*64 bf16 r*hx
  ushort* rh1  = rh0 + (size_t)MM * 64;
  ushort* rh2  = rh1 + (size_t)MM * 64;
  float*  ru   = (float*)(rh2 + (size_t)MM * 64);  // MM*128 fp32 gates
  ushort* Wtru = (ushort*)(ru + (size_t)MM * 128); // 128*384
  ushort* Wtc  = Wtru + 128 * 384;                 // 64*384
  uint2*  edges = (uint2*)(Wtc + 64 * 384);        // EE
  int*    cnt  = (int*)(edges + EE);
  int*    off  = cnt + NB;                         // NB+1
  int*    cur  = off + NB + 1;

  // CSR build (ws is re-poisoned before every launch; rebuild each call)
  hipMemsetAsync(cnt, 0, NB * sizeof(int), stream);
  k_count<<<(EE + 255) / 256, 256, 0, stream>>>(dst, cnt);
  k_scan<<<1, 1024, 0, stream>>>(cnt, off, cur);
  k_fill<<<(EE + 255) / 256, 256, 0, stream>>>(src, dst, d_ker, cur, edges);
  k_convW<<<(128 * 384 + 255) / 256, 256, 0, stream>>>(d_Wru, d_Wc, Wtru, Wtc);

  // conv 1: [in|hx] -> prop x2 (128ch) -> sigmoid gates
  k_build_xru<<<(MM * 16) / 256, 256, 0, stream>>>(d_inputs, d_hx, x);
  k_prop<<<(NB * 64) / 256, 256, 0, stream>>>(x, y1, off, edges);
  k_prop<<<(NB * 64) / 256, 256, 0, stream>>>(y1, y2, off, edges);
  ViewTab V1;
  for (int t = 0; t < 12; ++t) {
    const ushort* ten = (t < 4) ? x : (t < 8) ? y1 : y2;
    V1.base[t] = ten + (t & 3) * 32;
    V1.stride[t] = 128;
  }
  k_gemm_mfma<4, false><<<MM / 64, 256, 0, stream>>>(V1, Wtru, d_bru, ru, nullptr, nullptr);

  // conv 2: reuse propagated `in` halves of x/y1/y2; propagate only r*hx (64ch)
  k_build_rh<<<(MM * 8) / 256, 256, 0, stream>>>(ru, d_hx, rh0);
  k_prop64<<<(NB * 32) / 256, 256, 0, stream>>>(rh0, rh1, off, edges);
  k_prop64<<<(NB * 32) / 256, 256, 0, stream>>>(rh1, rh2, off, edges);
  ViewTab V2;
  {
    const ushort* c1[3] = {x, y1, y2};
    const ushort* c2[3] = {rh0, rh1, rh2};
    for (int v = 0; v < 3; ++v) {
      V2.base[v * 4 + 0] = c1[v];      V2.stride[v * 4 + 0] = 128;
      V2.base[v * 4 + 1] = c1[v] + 32; V2.stride[v * 4 + 1] = 128;
      V2.base[v * 4 + 2] = c2[v];      V2.stride[v * 4 + 2] = 64;
      V2.base[v * 4 + 3] = c2[v] + 32; V2.stride[v * 4 + 3] = 64;
    }
  }
  k_gemm_mfma<2, true><<<MM / 64, 256, 0, stream>>>(V2, Wtc, d_bc, ru, d_hx, out);
}